// Round 19
// baseline (76.980 us; speedup 1.0000x reference)
//
#include <hip/hip_runtime.h>
#include <hip/hip_bf16.h>
#include <stdint.h>

// Upsample2x(nearest) + Conv3x3(pad1) + bias via the parity trick:
//   out[b,co,2r+py,2s+px] = bias[co] +
//     sum_{ky,kx in {0,1}, ci} weff[py,px][co][ky,kx,ci] * xpad[b, r+py+ky, s+px+kx, ci]
// 4 parity GEMMs: M=512(co) x N=8192(b,r,s) x K=2048.
// R19 = R14/R18 skeleton with AGED GATES: ST_A and ST_B for tile T+2 (T+3)
// are issued TOGETHER at the mid-tile position (right after the mid-BAR,
// where both destination regions are provably dead), and the steady gates
// widen vmcnt(4)->vmcnt(8). FIFO effect: every gate now forces only loads
// issued a FULL tile (~4 phases, ~2000cy) earlier instead of ~1.5 phases ->
// gate stalls ~0. Everything else identical to the measured-best R14:
// BM=BN=256, BK=64, 8 waves (2Mx4N), 128KB LDS 2-slot dbuf, distance-1
// register pipeline, wave-skewed phase order (wr=0 read-first, wr=1
// MFMA-first), 8-slot XOR swizzle on BOTH staging source and ds_read
// (rule #21), px-twin XCD map, fused single-launch prep.

typedef __attribute__((ext_vector_type(8)))  __bf16 bf16x8;
typedef __attribute__((ext_vector_type(4)))  float  f32x4;
typedef __attribute__((ext_vector_type(4)))  int    int4v;

__device__ __forceinline__ void async16(const void* g, void* l) {
  __builtin_amdgcn_global_load_lds(
      (const __attribute__((address_space(1))) void*)g,
      (__attribute__((address_space(3))) void*)l,
      16, 0, 0);
}

// ---------------------------------------------------------------------------
// fused_prep: grid = 3336 blocks x 256 threads (unchanged from R8)
__global__ void fused_prep(const float* __restrict__ x,
                           const float* __restrict__ w,
                           __hip_bfloat16* __restrict__ xpad,
                           __hip_bfloat16* __restrict__ weff) {
  const int bid = blockIdx.x;
  const int tid = threadIdx.x;
  __shared__ __align__(16) __hip_bfloat16 ldsT[32][80];

  if (bid < 2048) {
    const int blk = bid;
    const int cib = blk & 7;
    const int r   = (blk >> 3) & 31;
    const int b   = blk >> 8;
    const int ci_l = tid >> 2;
    const int wq   = tid & 3;
    const float* xp = x + (((size_t)(b * 512 + cib * 64 + ci_l) * 32 + r) * 32) + wq * 8;
    float4 v0 = *(const float4*)(xp);
    float4 v1 = *(const float4*)(xp + 4);
    const int wb = wq * 8;
    ldsT[wb + 0][ci_l] = __float2bfloat16(v0.x);
    ldsT[wb + 1][ci_l] = __float2bfloat16(v0.y);
    ldsT[wb + 2][ci_l] = __float2bfloat16(v0.z);
    ldsT[wb + 3][ci_l] = __float2bfloat16(v0.w);
    ldsT[wb + 4][ci_l] = __float2bfloat16(v1.x);
    ldsT[wb + 5][ci_l] = __float2bfloat16(v1.y);
    ldsT[wb + 6][ci_l] = __float2bfloat16(v1.z);
    ldsT[wb + 7][ci_l] = __float2bfloat16(v1.w);
    __syncthreads();
    const int w_o = tid >> 3;
    const int ch  = tid & 7;
    char* dst = (char*)xpad +
        ((((size_t)(b * 34 + (r + 1)) * 34) + (w_o + 1)) * 512 + cib * 64 + ch * 8) * 2;
    *(int4v*)dst = *(const int4v*)&ldsT[w_o][ch * 8];
  } else if (bid < 3072) {
    const int idx = (bid - 2048) * 256 + tid;
    const float* wp = w + (size_t)idx * 9;
    const int co = idx >> 9;
    const int ci = idx & 511;
    float t[9];
#pragma unroll
    for (int i = 0; i < 9; ++i) t[i] = wp[i];
#pragma unroll
    for (int py = 0; py < 2; ++py) {
#pragma unroll
      for (int px = 0; px < 2; ++px) {
        const int p = py * 2 + px;
#pragma unroll
        for (int ky = 0; ky < 2; ++ky) {
          const int ulo = (ky == 0) ? 0 : (py == 0 ? 1 : 2);
          const int uhi = (ky == 0) ? (py == 0 ? 0 : 1) : 2;
#pragma unroll
          for (int kx = 0; kx < 2; ++kx) {
            const int vlo = (kx == 0) ? 0 : (px == 0 ? 1 : 2);
            const int vhi = (kx == 0) ? (px == 0 ? 0 : 1) : 2;
            float s = 0.f;
            for (int u = ulo; u <= uhi; ++u)
              for (int v = vlo; v <= vhi; ++v)
                s += t[u * 3 + v];
            const int kk = ky * 2 + kx;
            weff[(((size_t)p * 512 + co) * 4 + kk) * 512 + ci] = __float2bfloat16(s);
          }
        }
      }
    }
  } else if (bid < 3208) {
    const int f  = (bid - 3072) * 2048 + tid * 8;
    const int b  = f / 34816;
    const int rr = (f / 17408) & 1;
    const int off = f % 17408;
    __hip_bfloat16* dst = xpad + ((size_t)(b * 34 + rr * 33) * 17408) + off;
    int4v z = {0, 0, 0, 0};
    *(int4v*)dst = z;
  } else {
    const int f  = (bid - 3208) * 2048 + tid * 8;
    const int b  = f / 32768;
    const int cc = (f / 16384) & 1;
    const int r  = ((f / 512) & 31) + 1;
    const int ci = f & 511;
    __hip_bfloat16* dst = xpad +
        (((size_t)(b * 34 + r) * 34) + cc * 33) * 512 + ci;
    int4v z = {0, 0, 0, 0};
    *(int4v*)dst = z;
  }
}

// ---------------------------------------------------------------------------
// GEMM. LDS: A slot d @ d*32768, B @ 65536 + d*32768. Row layout: [rows][8 x
// 16B slots], phys slot = logical ^ (row&7); swizzle on BOTH sides (rule #21).
#define MM(a, b, c) __builtin_amdgcn_mfma_f32_16x16x32_bf16((a), (b), (c), 0, 0, 0)
#define BAR() asm volatile("s_barrier" ::: "memory")
#define PRIO(x) __builtin_amdgcn_s_setprio(x)
#define GATE(N) asm volatile("s_waitcnt vmcnt(" N ")" ::: "memory")

#define ST_A(T, d) do {                                                        \
    char* _l = lds + (d) * 32768 + dA;                                         \
    const __hip_bfloat16* _g = pA0 + (size_t)(T) * 64;                         \
    async16(_g, _l); async16(_g + 131072, _l + 8192);                          \
    async16(_g + 262144, _l + 16384); async16(_g + 393216, _l + 24576);        \
  } while (0)

#define OFFB(T) (((((T) >> 4) * 34) + (((T) >> 3) & 1)) * 512 + ((T) & 7) * 64)
#define ST_B(T, d) do {                                                        \
    char* _l = lds + 65536 + (d) * 32768 + dA;                                 \
    const int _o = OFFB(T);                                                    \
    async16(pB00 + _o, _l); async16(pB01 + _o, _l + 8192);                     \
    async16(pB10 + _o, _l + 16384); async16(pB11 + _o, _l + 24576);            \
  } while (0)

#define RD_A(D, S, mb) do {                                                    \
    _Pragma("unroll") for (int _m = 0; _m < 4; ++_m) {                         \
      (D)[_m * 2]     = *(const bf16x8*)((S) + ((mb) + _m) * 2048 + aoff0);    \
      (D)[_m * 2 + 1] = *(const bf16x8*)((S) + ((mb) + _m) * 2048 + aoff1); }  \
  } while (0)

#define RD_B(D, S, nb) do {                                                    \
    _Pragma("unroll") for (int _n = 0; _n < 2; ++_n) {                         \
      (D)[_n * 2]     = *(const bf16x8*)((S) + ((nb) + _n) * 2048 + aoff0);    \
      (D)[_n * 2 + 1] = *(const bf16x8*)((S) + ((nb) + _n) * 2048 + aoff1); }  \
  } while (0)

#define MFMAQ(mb, nb, A, B) do {                                               \
    _Pragma("unroll") for (int _m = 0; _m < 4; ++_m)                           \
      _Pragma("unroll") for (int _n = 0; _n < 2; ++_n) {                       \
        acc[(mb)+_m][(nb)+_n] = MM((A)[_m*2],   (B)[_n*2],   acc[(mb)+_m][(nb)+_n]); \
        acc[(mb)+_m][(nb)+_n] = MM((A)[_m*2+1], (B)[_n*2+1], acc[(mb)+_m][(nb)+_n]); } \
  } while (0)

// Hazard audit for mid-tile ST (both variants): ST_A(T+2,0)/ST_B(T+2,0) at
// even mid overwrite aS0/bS0 (tile T). Last reads of aS0: Ab(m4-7) even ph1;
// of bS0: Bb(n2-3) even ph1 (Ba(n0-1)/Aa(m0-3) were read in the PREVIOUS
// iteration) -- all before the even mid-BAR. Same for odd/slot1.
// FIFO at even gate: in-flight = T+1's 8 (issued prev odd mid) + T+2's 8
// (just issued) = 16; GATE(8) forces exactly T+1, each >=1 full tile old.
// Odd gate: in-flight = T+2's 8 + T+3's 8; GATE(8) forces T+2.

// ---- Read-first variant: ds_reads lead each phase.
#define ITER_RF(T, SE, SO, GE, GO, LAST) do {                                  \
  /* even tile: slot0 */                                                       \
  RD_A(Ab, aS0, 4);                                                            \
  PRIO(1); MFMAQ(0, 0, Aa, Ba); PRIO(0);                                       \
  RD_B(Bb, bS0, 2);                                                            \
  PRIO(1); MFMAQ(4, 0, Ab, Ba); PRIO(0);                                       \
  BAR();                                                                       \
  if (SE) { ST_A((T) + 2, 0); ST_B((T) + 2, 0); }                              \
  PRIO(1); MFMAQ(4, 2, Ab, Bb); PRIO(0);                                       \
  GATE(GE); BAR();                                                             \
  RD_A(Ab, aS1, 0); RD_B(Ba, bS1, 0);                                          \
  PRIO(1); MFMAQ(0, 2, Aa, Bb); PRIO(0);                                       \
  /* odd tile: slot1 */                                                        \
  RD_A(Aa, aS1, 4);                                                            \
  PRIO(1); MFMAQ(0, 0, Ab, Ba); PRIO(0);                                       \
  RD_B(Bb, bS1, 2);                                                            \
  PRIO(1); MFMAQ(4, 0, Aa, Ba); PRIO(0);                                       \
  BAR();                                                                       \
  if (SO) { ST_A((T) + 3, 1); ST_B((T) + 3, 1); }                              \
  PRIO(1); MFMAQ(4, 2, Aa, Bb); PRIO(0);                                       \
  GATE(GO); BAR();                                                             \
  if (!LAST) { RD_A(Aa, aS0, 0); RD_B(Ba, bS0, 0); }                           \
  PRIO(1); MFMAQ(0, 2, Ab, Bb); PRIO(0);                                       \
} while (0)

// ---- MFMA-first variant: same barriers/gates/staging positions, MFMA leads.
#define ITER_MF(T, SE, SO, GE, GO, LAST) do {                                  \
  /* even tile: slot0 */                                                       \
  PRIO(1); MFMAQ(0, 0, Aa, Ba); PRIO(0);                                       \
  RD_A(Ab, aS0, 4);                                                            \
  PRIO(1); MFMAQ(4, 0, Ab, Ba); PRIO(0);                                       \
  RD_B(Bb, bS0, 2);                                                            \
  BAR();                                                                       \
  if (SE) { ST_A((T) + 2, 0); ST_B((T) + 2, 0); }                              \
  PRIO(1); MFMAQ(4, 2, Ab, Bb); PRIO(0);                                       \
  GATE(GE); BAR();                                                             \
  PRIO(1); MFMAQ(0, 2, Aa, Bb); PRIO(0);                                       \
  RD_A(Ab, aS1, 0); RD_B(Ba, bS1, 0);                                          \
  /* odd tile: slot1 */                                                        \
  PRIO(1); MFMAQ(0, 0, Ab, Ba); PRIO(0);                                       \
  RD_A(Aa, aS1, 4);                                                            \
  PRIO(1); MFMAQ(4, 0, Aa, Ba); PRIO(0);                                       \
  RD_B(Bb, bS1, 2);                                                            \
  BAR();                                                                       \
  if (SO) { ST_A((T) + 3, 1); ST_B((T) + 3, 1); }                              \
  PRIO(1); MFMAQ(4, 2, Aa, Bb); PRIO(0);                                       \
  GATE(GO); BAR();                                                             \
  PRIO(1); MFMAQ(0, 2, Ab, Bb); PRIO(0);                                       \
  if (!LAST) { RD_A(Aa, aS0, 0); RD_B(Ba, bS0, 0); }                           \
} while (0)

__global__ __launch_bounds__(512, 1) void upconv_gemm(
    const __hip_bfloat16* __restrict__ xpad,   // [8][34][34][512]
    const __hip_bfloat16* __restrict__ weff,   // [4][512][2048]
    const float* __restrict__ bias,
    float* __restrict__ out) {                 // [8][512][64][64]
  extern __shared__ __align__(16) char lds[]; // 131072 B

  // px-twin XCD map: twin blocks (px=0/1, same nt) adjacent on one XCD.
  const int bid = blockIdx.x;
  const int g = bid & 7, i = bid >> 3;
  const int py = g >> 2;
  const int mt = (g >> 1) & 1;
  const int nh = g & 1;
  const int px = i & 1;
  const int nt = nh * 16 + (i >> 1);   // 0..31
  const int p  = py * 2 + px;
  const int co0 = mt << 8;
  const int n0  = nt << 8;
  const int b   = n0 >> 10;
  const int rb  = (n0 & 1023) >> 5;    // 0,8,16,24

  const int tid  = threadIdx.x;
  const int lane = tid & 63;
  const int wv   = tid >> 6;           // 0..7
  const int wr   = wv >> 2;            // M half; also the phase-skew selector
  const int wc   = wv & 3;             // N quarter (64 cols)

  // ---- staging: thread covers row srow of each 128-row half, phys slot
  // tid&7, fetching logical k-chunk sl = (tid&7)^(srow&7).
  const int srow = tid >> 3;           // 0..63
  const int sl   = (tid & 7) ^ (srow & 7);
  const int dA   = wv * 1024;          // wave-uniform LDS staging base

  const __hip_bfloat16* wpp = weff + ((size_t)p << 20);
  const __hip_bfloat16* pA0 = wpp + (size_t)(co0 + srow) * 2048 + sl * 8;
  const __hip_bfloat16* pB00 = xpad +
      ((size_t)(b * 34 + rb + (srow >> 5) + py) * 34 + (srow & 31) + px) * 512 + sl * 8;
  const __hip_bfloat16* pB01 = pB00 + (size_t)2 * 34 * 512;   // rows +64
  const __hip_bfloat16* pB10 = pB00 + (size_t)4 * 34 * 512;   // rows +128
  const __hip_bfloat16* pB11 = pB00 + (size_t)6 * 34 * 512;   // rows +192

  // ---- fragment ds_read addressing (swizzled)
  const int aoff0 = (lane & 15) * 128 + (((lane >> 4) ^ (lane & 7)) * 16);
  const int aoff1 = (lane & 15) * 128 + ((((lane >> 4) + 4) ^ (lane & 7)) * 16);
  const char* aS0 = lds + wr * 16384;
  const char* aS1 = aS0 + 32768;
  const char* bS0 = lds + 65536 + (wc >> 1) * 16384 + (wc & 1) * 8192;
  const char* bS1 = bS0 + 32768;

  f32x4 acc[8][4] = {};
  bf16x8 Aa[8], Ab[8], Ba[4], Bb[4];

  // ---- prologue: stage tiles 0 (slot0) and 1 (slot1); force tile 0; preload.
  ST_A(0, 0); ST_B(0, 0);
  ST_A(1, 1); ST_B(1, 1);
  GATE("8"); BAR();
  RD_A(Aa, aS0, 0); RD_B(Ba, bS0, 0);

  // ---- 16 iterations x 2 K-tiles = K 2048; wr selects the phase order.
  // Steady gates vmcnt(8): 16 in flight, forces only the full-tile-old 8.
  if (wr == 0) {
#pragma unroll 1
    for (int t = 0; t <= 28; t += 2) ITER_RF(t, true, true, "8", "8", false);
    ITER_RF(30, false, false, "0", "0", true);
  } else {
#pragma unroll 1
    for (int t = 0; t <= 28; t += 2) ITER_MF(t, true, true, "8", "8", false);
    ITER_MF(30, false, false, "0", "0", true);
  }

  // ---- epilogue: D layout row=(lane>>4)*4+j, col=lane&15 (m89)
#pragma unroll
  for (int m = 0; m < 8; ++m) {
    const int coB = co0 + wr * 128 + m * 16 + ((lane >> 4) << 2);
    float bv[4];
#pragma unroll
    for (int j = 0; j < 4; ++j) bv[j] = bias[coB + j];
#pragma unroll
    for (int nn = 0; nn < 4; ++nn) {
      const int nl = wc * 64 + nn * 16 + (lane & 15);
      const int rr = rb + (nl >> 5);
      const int ss = nl & 31;
      const int oh = rr * 2 + py;
      const int ow = ss * 2 + px;
      float* op = out + (((size_t)(b * 512 + coB) << 6) + oh) * 64 + ow;
#pragma unroll
      for (int j = 0; j < 4; ++j)
        op[(size_t)j * 4096] = acc[m][nn][j] + bv[j];
    }
  }
}

// ---------------------------------------------------------------------------
extern "C" void kernel_launch(void* const* d_in, const int* in_sizes, int n_in,
                              void* d_out, int out_size, void* d_ws, size_t ws_size,
                              hipStream_t stream) {
  (void)in_sizes; (void)n_in; (void)out_size; (void)ws_size;
  const float* x  = (const float*)d_in[0];   // [8][512][32][32]
  const float* w  = (const float*)d_in[1];   // [512][512][3][3]
  const float* bs = (const float*)d_in[2];   // [512]
  float* out = (float*)d_out;                // [8][512][64][64]
  char* ws = (char*)d_ws;
  __hip_bfloat16* xpad = (__hip_bfloat16*)ws;                 // 9,467,904 B
  __hip_bfloat16* weff = (__hip_bfloat16*)(ws + (10u << 20)); // 8,388,608 B
  fused_prep<<<dim3(3336), dim3(256), 0, stream>>>(x, w, xpad, weff);
  upconv_gemm<<<dim3(256), dim3(512), 131072, stream>>>(xpad, weff, bs, out);
}

// Round 20
// 73.212 us; speedup vs baseline: 1.0515x; 1.0515x over previous
//
#include <hip/hip_runtime.h>
#include <hip/hip_bf16.h>
#include <stdint.h>

// Upsample2x(nearest) + Conv3x3(pad1) + bias via the parity trick:
//   out[b,co,2r+py,2s+px] = bias[co] +
//     sum_{ky,kx in {0,1}, ci} weff[py,px][co][ky,kx,ci] * xpad[b, r+py+ky, s+px+kx, ci]
// 4 parity GEMMs: M=512(co) x N=8192(b,r,s) x K=2048.
// R20 = R18/R14 exact revert — the measured best across 19 rounds:
// total 73.5us; GEMM ~65us, MfmaUtil 42-44%, 0 bank conflicts.
// R19's aged-gates (clustered mid-tile staging burst) regressed -6 us and is
// reverted. GEMM: BM=BN=256, BK=64, 8 waves (2Mx4N), 128KB LDS 2-slot dbuf,
// distance-1 register pipeline, wave-skewed phase order (wr=0 read-first,
// wr=1 MFMA-first), 8-slot XOR swizzle on BOTH staging source and ds_read
// (rule #21), px-twin XCD map, fused single-launch prep.

typedef __attribute__((ext_vector_type(8)))  __bf16 bf16x8;
typedef __attribute__((ext_vector_type(4)))  float  f32x4;
typedef __attribute__((ext_vector_type(4)))  int    int4v;

__device__ __forceinline__ void async16(const void* g, void* l) {
  __builtin_amdgcn_global_load_lds(
      (const __attribute__((address_space(1))) void*)g,
      (__attribute__((address_space(3))) void*)l,
      16, 0, 0);
}

// ---------------------------------------------------------------------------
// fused_prep: grid = 3336 blocks x 256 threads
__global__ void fused_prep(const float* __restrict__ x,
                           const float* __restrict__ w,
                           __hip_bfloat16* __restrict__ xpad,
                           __hip_bfloat16* __restrict__ weff) {
  const int bid = blockIdx.x;
  const int tid = threadIdx.x;
  __shared__ __align__(16) __hip_bfloat16 ldsT[32][80];

  if (bid < 2048) {
    const int blk = bid;
    const int cib = blk & 7;
    const int r   = (blk >> 3) & 31;
    const int b   = blk >> 8;
    const int ci_l = tid >> 2;
    const int wq   = tid & 3;
    const float* xp = x + (((size_t)(b * 512 + cib * 64 + ci_l) * 32 + r) * 32) + wq * 8;
    float4 v0 = *(const float4*)(xp);
    float4 v1 = *(const float4*)(xp + 4);
    const int wb = wq * 8;
    ldsT[wb + 0][ci_l] = __float2bfloat16(v0.x);
    ldsT[wb + 1][ci_l] = __float2bfloat16(v0.y);
    ldsT[wb + 2][ci_l] = __float2bfloat16(v0.z);
    ldsT[wb + 3][ci_l] = __float2bfloat16(v0.w);
    ldsT[wb + 4][ci_l] = __float2bfloat16(v1.x);
    ldsT[wb + 5][ci_l] = __float2bfloat16(v1.y);
    ldsT[wb + 6][ci_l] = __float2bfloat16(v1.z);
    ldsT[wb + 7][ci_l] = __float2bfloat16(v1.w);
    __syncthreads();
    const int w_o = tid >> 3;
    const int ch  = tid & 7;
    char* dst = (char*)xpad +
        ((((size_t)(b * 34 + (r + 1)) * 34) + (w_o + 1)) * 512 + cib * 64 + ch * 8) * 2;
    *(int4v*)dst = *(const int4v*)&ldsT[w_o][ch * 8];
  } else if (bid < 3072) {
    const int idx = (bid - 2048) * 256 + tid;
    const float* wp = w + (size_t)idx * 9;
    const int co = idx >> 9;
    const int ci = idx & 511;
    float t[9];
#pragma unroll
    for (int i = 0; i < 9; ++i) t[i] = wp[i];
#pragma unroll
    for (int py = 0; py < 2; ++py) {
#pragma unroll
      for (int px = 0; px < 2; ++px) {
        const int p = py * 2 + px;
#pragma unroll
        for (int ky = 0; ky < 2; ++ky) {
          const int ulo = (ky == 0) ? 0 : (py == 0 ? 1 : 2);
          const int uhi = (ky == 0) ? (py == 0 ? 0 : 1) : 2;
#pragma unroll
          for (int kx = 0; kx < 2; ++kx) {
            const int vlo = (kx == 0) ? 0 : (px == 0 ? 1 : 2);
            const int vhi = (kx == 0) ? (px == 0 ? 0 : 1) : 2;
            float s = 0.f;
            for (int u = ulo; u <= uhi; ++u)
              for (int v = vlo; v <= vhi; ++v)
                s += t[u * 3 + v];
            const int kk = ky * 2 + kx;
            weff[(((size_t)p * 512 + co) * 4 + kk) * 512 + ci] = __float2bfloat16(s);
          }
        }
      }
    }
  } else if (bid < 3208) {
    const int f  = (bid - 3072) * 2048 + tid * 8;
    const int b  = f / 34816;
    const int rr = (f / 17408) & 1;
    const int off = f % 17408;
    __hip_bfloat16* dst = xpad + ((size_t)(b * 34 + rr * 33) * 17408) + off;
    int4v z = {0, 0, 0, 0};
    *(int4v*)dst = z;
  } else {
    const int f  = (bid - 3208) * 2048 + tid * 8;
    const int b  = f / 32768;
    const int cc = (f / 16384) & 1;
    const int r  = ((f / 512) & 31) + 1;
    const int ci = f & 511;
    __hip_bfloat16* dst = xpad +
        (((size_t)(b * 34 + r) * 34) + cc * 33) * 512 + ci;
    int4v z = {0, 0, 0, 0};
    *(int4v*)dst = z;
  }
}

// ---------------------------------------------------------------------------
// GEMM. LDS: A slot d @ d*32768, B @ 65536 + d*32768. Row layout: [rows][8 x
// 16B slots], phys slot = logical ^ (row&7); swizzle on BOTH sides (rule #21).
#define MM(a, b, c) __builtin_amdgcn_mfma_f32_16x16x32_bf16((a), (b), (c), 0, 0, 0)
#define BAR() asm volatile("s_barrier" ::: "memory")
#define PRIO(x) __builtin_amdgcn_s_setprio(x)
#define GATE(N) asm volatile("s_waitcnt vmcnt(" N ")" ::: "memory")

#define ST_A(T, d) do {                                                        \
    char* _l = lds + (d) * 32768 + dA;                                         \
    const __hip_bfloat16* _g = pA0 + (size_t)(T) * 64;                         \
    async16(_g, _l); async16(_g + 131072, _l + 8192);                          \
    async16(_g + 262144, _l + 16384); async16(_g + 393216, _l + 24576);        \
  } while (0)

#define OFFB(T) (((((T) >> 4) * 34) + (((T) >> 3) & 1)) * 512 + ((T) & 7) * 64)
#define ST_B(T, d) do {                                                        \
    char* _l = lds + 65536 + (d) * 32768 + dA;                                 \
    const int _o = OFFB(T);                                                    \
    async16(pB00 + _o, _l); async16(pB01 + _o, _l + 8192);                     \
    async16(pB10 + _o, _l + 16384); async16(pB11 + _o, _l + 24576);            \
  } while (0)

#define RD_A(D, S, mb) do {                                                    \
    _Pragma("unroll") for (int _m = 0; _m < 4; ++_m) {                         \
      (D)[_m * 2]     = *(const bf16x8*)((S) + ((mb) + _m) * 2048 + aoff0);    \
      (D)[_m * 2 + 1] = *(const bf16x8*)((S) + ((mb) + _m) * 2048 + aoff1); }  \
  } while (0)

#define RD_B(D, S, nb) do {                                                    \
    _Pragma("unroll") for (int _n = 0; _n < 2; ++_n) {                         \
      (D)[_n * 2]     = *(const bf16x8*)((S) + ((nb) + _n) * 2048 + aoff0);    \
      (D)[_n * 2 + 1] = *(const bf16x8*)((S) + ((nb) + _n) * 2048 + aoff1); }  \
  } while (0)

#define MFMAQ(mb, nb, A, B) do {                                               \
    _Pragma("unroll") for (int _m = 0; _m < 4; ++_m)                           \
      _Pragma("unroll") for (int _n = 0; _n < 2; ++_n) {                       \
        acc[(mb)+_m][(nb)+_n] = MM((A)[_m*2],   (B)[_n*2],   acc[(mb)+_m][(nb)+_n]); \
        acc[(mb)+_m][(nb)+_n] = MM((A)[_m*2+1], (B)[_n*2+1], acc[(mb)+_m][(nb)+_n]); } \
  } while (0)

// ---- Read-first variant (R8 order): ds_reads lead each phase.
#define ITER_RF(T, SE, SO, GE, GO, LAST) do {                                  \
  /* even tile: slot0 */                                                       \
  RD_A(Ab, aS0, 4);                                                            \
  PRIO(1); MFMAQ(0, 0, Aa, Ba); PRIO(0);                                       \
  RD_B(Bb, bS0, 2);                                                            \
  PRIO(1); MFMAQ(4, 0, Ab, Ba); PRIO(0);                                       \
  BAR();                                                                       \
  if (SE) ST_A((T) + 2, 0);                                                    \
  PRIO(1); MFMAQ(4, 2, Ab, Bb); PRIO(0);                                       \
  GATE(GE); BAR();                                                             \
  RD_A(Ab, aS1, 0); RD_B(Ba, bS1, 0);                                          \
  if (SE) ST_B((T) + 2, 0);                                                    \
  PRIO(1); MFMAQ(0, 2, Aa, Bb); PRIO(0);                                       \
  /* odd tile: slot1 */                                                        \
  RD_A(Aa, aS1, 4);                                                            \
  PRIO(1); MFMAQ(0, 0, Ab, Ba); PRIO(0);                                       \
  RD_B(Bb, bS1, 2);                                                            \
  PRIO(1); MFMAQ(4, 0, Aa, Ba); PRIO(0);                                       \
  BAR();                                                                       \
  if (SO) ST_A((T) + 3, 1);                                                    \
  PRIO(1); MFMAQ(4, 2, Aa, Bb); PRIO(0);                                       \
  GATE(GO); BAR();                                                             \
  if (!LAST) { RD_A(Aa, aS0, 0); RD_B(Ba, bS0, 0); }                           \
  if (SO) ST_B((T) + 3, 1);                                                    \
  PRIO(1); MFMAQ(0, 2, Ab, Bb); PRIO(0);                                       \
} while (0)

// ---- MFMA-first variant: same barriers/gates/staging, MFMA leads each phase.
#define ITER_MF(T, SE, SO, GE, GO, LAST) do {                                  \
  /* even tile: slot0 */                                                       \
  PRIO(1); MFMAQ(0, 0, Aa, Ba); PRIO(0);                                       \
  RD_A(Ab, aS0, 4);                                                            \
  PRIO(1); MFMAQ(4, 0, Ab, Ba); PRIO(0);                                       \
  RD_B(Bb, bS0, 2);                                                            \
  BAR();                                                                       \
  PRIO(1); MFMAQ(4, 2, Ab, Bb); PRIO(0);                                       \
  if (SE) ST_A((T) + 2, 0);                                                    \
  GATE(GE); BAR();                                                             \
  PRIO(1); MFMAQ(0, 2, Aa, Bb); PRIO(0);                                       \
  RD_A(Ab, aS1, 0); RD_B(Ba, bS1, 0);                                          \
  if (SE) ST_B((T) + 2, 0);                                                    \
  /* odd tile: slot1 */                                                        \
  PRIO(1); MFMAQ(0, 0, Ab, Ba); PRIO(0);                                       \
  RD_A(Aa, aS1, 4);                                                            \
  PRIO(1); MFMAQ(4, 0, Aa, Ba); PRIO(0);                                       \
  RD_B(Bb, bS1, 2);                                                            \
  BAR();                                                                       \
  PRIO(1); MFMAQ(4, 2, Aa, Bb); PRIO(0);                                       \
  if (SO) ST_A((T) + 3, 1);                                                    \
  GATE(GO); BAR();                                                             \
  PRIO(1); MFMAQ(0, 2, Ab, Bb); PRIO(0);                                       \
  if (!LAST) { RD_A(Aa, aS0, 0); RD_B(Ba, bS0, 0); }                           \
  if (SO) ST_B((T) + 3, 1);                                                    \
} while (0)

__global__ __launch_bounds__(512, 1) void upconv_gemm(
    const __hip_bfloat16* __restrict__ xpad,   // [8][34][34][512]
    const __hip_bfloat16* __restrict__ weff,   // [4][512][2048]
    const float* __restrict__ bias,
    float* __restrict__ out) {                 // [8][512][64][64]
  extern __shared__ __align__(16) char lds[]; // 131072 B

  // px-twin XCD map: twin blocks (px=0/1, same nt) adjacent on one XCD.
  const int bid = blockIdx.x;
  const int g = bid & 7, i = bid >> 3;
  const int py = g >> 2;
  const int mt = (g >> 1) & 1;
  const int nh = g & 1;
  const int px = i & 1;
  const int nt = nh * 16 + (i >> 1);   // 0..31
  const int p  = py * 2 + px;
  const int co0 = mt << 8;
  const int n0  = nt << 8;
  const int b   = n0 >> 10;
  const int rb  = (n0 & 1023) >> 5;    // 0,8,16,24

  const int tid  = threadIdx.x;
  const int lane = tid & 63;
  const int wv   = tid >> 6;           // 0..7
  const int wr   = wv >> 2;            // M half; also the phase-skew selector
  const int wc   = wv & 3;             // N quarter (64 cols)

  // ---- staging: thread covers row srow of each 128-row half, phys slot
  // tid&7, fetching logical k-chunk sl = (tid&7)^(srow&7).
  const int srow = tid >> 3;           // 0..63
  const int sl   = (tid & 7) ^ (srow & 7);
  const int dA   = wv * 1024;          // wave-uniform LDS staging base

  const __hip_bfloat16* wpp = weff + ((size_t)p << 20);
  const __hip_bfloat16* pA0 = wpp + (size_t)(co0 + srow) * 2048 + sl * 8;
  const __hip_bfloat16* pB00 = xpad +
      ((size_t)(b * 34 + rb + (srow >> 5) + py) * 34 + (srow & 31) + px) * 512 + sl * 8;
  const __hip_bfloat16* pB01 = pB00 + (size_t)2 * 34 * 512;   // rows +64
  const __hip_bfloat16* pB10 = pB00 + (size_t)4 * 34 * 512;   // rows +128
  const __hip_bfloat16* pB11 = pB00 + (size_t)6 * 34 * 512;   // rows +192

  // ---- fragment ds_read addressing (swizzled)
  const int aoff0 = (lane & 15) * 128 + (((lane >> 4) ^ (lane & 7)) * 16);
  const int aoff1 = (lane & 15) * 128 + ((((lane >> 4) + 4) ^ (lane & 7)) * 16);
  const char* aS0 = lds + wr * 16384;
  const char* aS1 = aS0 + 32768;
  const char* bS0 = lds + 65536 + (wc >> 1) * 16384 + (wc & 1) * 8192;
  const char* bS1 = bS0 + 32768;

  f32x4 acc[8][4] = {};
  bf16x8 Aa[8], Ab[8], Ba[4], Bb[4];

  // ---- prologue: stage tiles 0 (slot0) and 1 (slot1); force tile 0; preload.
  ST_A(0, 0); ST_B(0, 0);
  ST_A(1, 1); ST_B(1, 1);
  GATE("8"); BAR();
  RD_A(Aa, aS0, 0); RD_B(Ba, bS0, 0);

  // ---- 16 iterations x 2 K-tiles = K 2048; wr selects the phase order.
  if (wr == 0) {
#pragma unroll 1
    for (int t = 0; t <= 28; t += 2) ITER_RF(t, true, true, "4", "4", false);
    ITER_RF(30, false, false, "0", "0", true);
  } else {
#pragma unroll 1
    for (int t = 0; t <= 28; t += 2) ITER_MF(t, true, true, "4", "4", false);
    ITER_MF(30, false, false, "0", "0", true);
  }

  // ---- epilogue: D layout row=(lane>>4)*4+j, col=lane&15 (m89)
#pragma unroll
  for (int m = 0; m < 8; ++m) {
    const int coB = co0 + wr * 128 + m * 16 + ((lane >> 4) << 2);
    float bv[4];
#pragma unroll
    for (int j = 0; j < 4; ++j) bv[j] = bias[coB + j];
#pragma unroll
    for (int nn = 0; nn < 4; ++nn) {
      const int nl = wc * 64 + nn * 16 + (lane & 15);
      const int rr = rb + (nl >> 5);
      const int ss = nl & 31;
      const int oh = rr * 2 + py;
      const int ow = ss * 2 + px;
      float* op = out + (((size_t)(b * 512 + coB) << 6) + oh) * 64 + ow;
#pragma unroll
      for (int j = 0; j < 4; ++j)
        op[(size_t)j * 4096] = acc[m][nn][j] + bv[j];
    }
  }
}

// ---------------------------------------------------------------------------
extern "C" void kernel_launch(void* const* d_in, const int* in_sizes, int n_in,
                              void* d_out, int out_size, void* d_ws, size_t ws_size,
                              hipStream_t stream) {
  (void)in_sizes; (void)n_in; (void)out_size; (void)ws_size;
  const float* x  = (const float*)d_in[0];   // [8][512][32][32]
  const float* w  = (const float*)d_in[1];   // [512][512][3][3]
  const float* bs = (const float*)d_in[2];   // [512]
  float* out = (float*)d_out;                // [8][512][64][64]
  char* ws = (char*)d_ws;
  __hip_bfloat16* xpad = (__hip_bfloat16*)ws;                 // 9,467,904 B
  __hip_bfloat16* weff = (__hip_bfloat16*)(ws + (10u << 20)); // 8,388,608 B
  fused_prep<<<dim3(3336), dim3(256), 0, stream>>>(x, w, xpad, weff);
  upconv_gemm<<<dim3(256), dim3(512), 131072, stream>>>(xpad, weff, bs, out);
}